// Round 1
// 1292.557 us; speedup vs baseline: 1.3029x; 1.3029x over previous
//
#include <hip/hip_runtime.h>

// Problem sizes (fixed by the reference)
#define NA   100000
#define EB   200000
#define EBG  400000
#define NF   20000
#define EF   60000
#define EFBG 120000

typedef __attribute__((ext_vector_type(8))) short short8;   // 8 x bf16 (4 VGPRs)
typedef __attribute__((ext_vector_type(4))) float f32x4;

__device__ __forceinline__ float bf2f(unsigned short u) {
    union { unsigned int i; float f; } c; c.i = ((unsigned int)u) << 16; return c.f;
}
__device__ __forceinline__ unsigned short f2bf(float f) {
    union { float f; unsigned int i; } c; c.f = f;
    unsigned int x = c.i + 0x7FFFu + ((c.i >> 16) & 1u);   // RNE
    return (unsigned short)(x >> 16);
}
__device__ __forceinline__ float lrelu(float v) { return v > 0.f ? v : 0.2f * v; }

// ---------------------------------------------------------------------------
// prep_w: convert W (256x256 f32, row-major [n][k]) to bf16 pre-swizzled into
// MFMA B-fragment order. Fragment id = wv*16 + ks*2 + nt  (wv=wave 0..7 owning
// cols wv*32.., ks=K-subtile 0..7, nt=n-tile 0..1). Element for lane (q,c):
//   B[n = wv*32 + nt*16 + c][k = ks*32 + q*8 + j], j=0..7  (C = A @ W^T)
// Layout: wf[(fid*64 + lane)*8 + j]  -> gemm loads one short8 per frag, coalesced.
// ---------------------------------------------------------------------------
__global__ void prep_w(const float* __restrict__ W, unsigned short* __restrict__ wf)
{
    int idx = blockIdx.x * blockDim.x + threadIdx.x;   // 8192 threads
    int lane = idx & 63;
    int fid  = idx >> 6;                               // 0..127
    int nt = fid & 1, ks = (fid >> 1) & 7, wv = fid >> 4;
    int n = wv * 32 + nt * 16 + (lane & 15);
    int k = ks * 32 + (lane >> 4) * 8;
    const float* src = W + (size_t)n * 256 + k;
    unsigned short* dst = wf + (size_t)idx * 8;
    ushort4 lo, hi;
    lo.x = f2bf(src[0]); lo.y = f2bf(src[1]); lo.z = f2bf(src[2]); lo.w = f2bf(src[3]);
    hi.x = f2bf(src[4]); hi.y = f2bf(src[5]); hi.z = f2bf(src[6]); hi.w = f2bf(src[7]);
    *(ushort4*)dst = lo; *(ushort4*)(dst + 4) = hi;
}

// ---------------------------------------------------------------------------
// GEMM v2: H = bf16( A(Mx256) @ W(256,256)^T + bias )
// 512 threads = 8 waves; wave wv owns cols [wv*32, wv*32+32).
// B fragments register-resident (loaded once per block from prep_w buffer).
// Grid-stride over M-tiles of 32 rows (all M here are multiples of 32).
// Per tile: stage A f32->bf16 into LDS (cvt_pk), 8 ks x 4 MFMA per wave, store.
// LDS row stride 264 shorts -> ds_read_b128 lands 2-way on banks (free).
// ---------------------------------------------------------------------------
#define GBM  32
#define GLDB 264

__global__ __launch_bounds__(512, 2) void gemm_bf16_v2(const float* __restrict__ A,
        const unsigned short* __restrict__ WF, const float* __restrict__ bias,
        unsigned short* __restrict__ Hout, int M)
{
    __shared__ __align__(16) unsigned short sA[GBM * GLDB];
    const int tid = threadIdx.x;
    const int wv = tid >> 6, lane = tid & 63;
    const int q = lane >> 4, c = lane & 15;

    // B fragments: 16 per wave = 64 VGPRs, loaded once (L2-resident 128KB)
    short8 bfr[8][2];
#pragma unroll
    for (int ks = 0; ks < 8; ++ks)
#pragma unroll
        for (int nt = 0; nt < 2; ++nt)
            bfr[ks][nt] = *(const short8*)(WF + (((size_t)((wv * 16 + ks * 2 + nt) * 64 + lane)) << 3));

    const float b0 = bias[wv * 32 + c];
    const float b1 = bias[wv * 32 + 16 + c];

    const int ntiles = M >> 5;
    for (int t = blockIdx.x; t < ntiles; t += gridDim.x) {
        const float* At = A + (size_t)t * GBM * 256;
        // stage 32x256 f32 -> bf16 LDS; each thread 4 coalesced float4 loads
#pragma unroll
        for (int i = 0; i < 4; ++i) {
            int f4 = tid + i * 512;
            int row = f4 >> 6, col = (f4 & 63) << 2;     // col in floats
            f32x4 v = *(const f32x4*)(At + row * 256 + col);
            union { ushort4 u4; unsigned int u[2]; } pk;
            asm("v_cvt_pk_bf16_f32 %0, %1, %2" : "=v"(pk.u[0]) : "v"(v.x), "v"(v.y));
            asm("v_cvt_pk_bf16_f32 %0, %1, %2" : "=v"(pk.u[1]) : "v"(v.z), "v"(v.w));
            *(ushort4*)&sA[row * GLDB + col] = pk.u4;
        }
        __syncthreads();

        f32x4 acc00 = (f32x4){0.f,0.f,0.f,0.f}, acc01 = (f32x4){0.f,0.f,0.f,0.f};
        f32x4 acc10 = (f32x4){0.f,0.f,0.f,0.f}, acc11 = (f32x4){0.f,0.f,0.f,0.f};
#pragma unroll
        for (int ks = 0; ks < 8; ++ks) {
            short8 a0 = *(const short8*)&sA[(c)      * GLDB + ks * 32 + q * 8];
            short8 a1 = *(const short8*)&sA[(16 + c) * GLDB + ks * 32 + q * 8];
            acc00 = __builtin_amdgcn_mfma_f32_16x16x32_bf16(a0, bfr[ks][0], acc00, 0, 0, 0);
            acc01 = __builtin_amdgcn_mfma_f32_16x16x32_bf16(a0, bfr[ks][1], acc01, 0, 0, 0);
            acc10 = __builtin_amdgcn_mfma_f32_16x16x32_bf16(a1, bfr[ks][0], acc10, 0, 0, 0);
            acc11 = __builtin_amdgcn_mfma_f32_16x16x32_bf16(a1, bfr[ks][1], acc11, 0, 0, 0);
        }
        __syncthreads();

        // epilogue: C/D layout col=lane&15, row=quad*4+reg  [m89-verified]
        unsigned short* Ht = Hout + (size_t)t * GBM * 256;
        const int col0 = wv * 32 + c, col1 = wv * 32 + 16 + c;
#pragma unroll
        for (int r = 0; r < 4; ++r) {
            int row0 = (q * 4 + r) * 256;
            int row1 = (16 + q * 4 + r) * 256;
            Ht[row0 + col0] = f2bf(acc00[r] + b0);
            Ht[row0 + col1] = f2bf(acc01[r] + b1);
            Ht[row1 + col0] = f2bf(acc10[r] + b0);
            Ht[row1 + col1] = f2bf(acc11[r] + b1);
        }
    }
}

// ---------------------------------------------------------------------------
// Per-node alpha terms: at[n,h] = <h[n,h,:], w[h, 0:64]>, as[n,h] = <h[n,h,:], w[h, wsoff:wsoff+64]>
// One wave per node; lane l covers dims 4l..4l+3 (head = l/16); 16-lane reduce.
// ---------------------------------------------------------------------------
__global__ void node_alpha(const unsigned short* __restrict__ Hn, const float* __restrict__ w,
        int wstride, int wsoff, float* __restrict__ at, float* __restrict__ asr, int N)
{
    int gw = (blockIdx.x * blockDim.x + threadIdx.x) >> 6;
    int lane = threadIdx.x & 63;
    if (gw >= N) return;
    int hl = lane >> 4, l16 = lane & 15;
    ushort4 hu = *(const ushort4*)(Hn + (size_t)gw * 256 + lane * 4);
    float h0 = bf2f(hu.x), h1 = bf2f(hu.y), h2 = bf2f(hu.z), h3 = bf2f(hu.w);
    const float* wt = w + hl * wstride + l16 * 4;
    const float* wsv = wt + wsoff;
    float pt = h0 * wt[0] + h1 * wt[1] + h2 * wt[2] + h3 * wt[3];
    float ps = h0 * wsv[0] + h1 * wsv[1] + h2 * wsv[2] + h3 * wsv[3];
#pragma unroll
    for (int o = 1; o < 16; o <<= 1) { pt += __shfl_xor(pt, o); ps += __shfl_xor(ps, o); }
    if (l16 == 0) { at[(size_t)gw * 4 + hl] = pt; asr[(size_t)gw * 4 + hl] = ps; }
}

// tiny per-launch constant folding:
// cst[0..3]=c1b (x * this per head), cst[4..7]=c0b, cst[8..39]=d1fb[h*8+k], cst[40..43]=c0fb
__global__ void compute_consts(const float* __restrict__ a_b, const float* __restrict__ W_eab,
        const float* __restrict__ b_eab, const float* __restrict__ f_a_b,
        const float* __restrict__ W_eafb, const float* __restrict__ b_eafb, float* __restrict__ cst)
{
    int t = threadIdx.x;
    if (t < 4) {
        float s1 = 0.f, s0 = 0.f, sc = 0.f;
        for (int d = 0; d < 64; ++d) {
            float we = a_b[t * 192 + 64 + d];
            s1 += we * W_eab[d];
            s0 += we * b_eab[d];
            sc += f_a_b[t * 192 + 64 + d] * b_eafb[d];
        }
        cst[t] = s1; cst[4 + t] = s0; cst[40 + t] = sc;
    }
    if (t < 32) {
        int h = t >> 3, k = t & 7;
        float s = 0.f;
        for (int d = 0; d < 64; ++d) s += f_a_b[h * 192 + 64 + d] * W_eafb[d * 8 + k];
        cst[8 + t] = s;
    }
}

// bond-graph logits: edge attr is scalar -> eterm = x*c1[h] + c0[h]
__global__ void logits_bond(const int* __restrict__ eibg, const float* __restrict__ eab,
        const float* __restrict__ at, const float* __restrict__ asr,
        const float* __restrict__ cst, float* __restrict__ lg, int E)
{
    int e = blockIdx.x * blockDim.x + threadIdx.x;
    if (e >= E) return;
    int t = eibg[e], s = eibg[E + e];     // tgt = row0, src = row1
    float x = eab[e];
    float4 lt = *(const float4*)(at + (size_t)t * 4);
    float4 ls = *(const float4*)(asr + (size_t)s * 4);
    float4 o;
    o.x = lrelu(lt.x + ls.x + x * cst[0] + cst[4]);
    o.y = lrelu(lt.y + ls.y + x * cst[1] + cst[5]);
    o.z = lrelu(lt.z + ls.z + x * cst[2] + cst[6]);
    o.w = lrelu(lt.w + ls.w + x * cst[3] + cst[7]);
    *(float4*)(lg + (size_t)e * 4) = o;
}

// fbond-graph logits: 8-dim edge attr -> eterm = x8 . d1[h] + c0[h]
__global__ void logits_fbond(const int* __restrict__ eifbg, const float* __restrict__ eafb,
        const float* __restrict__ at, const float* __restrict__ asr,
        const float* __restrict__ cst, float* __restrict__ lg, int E)
{
    int e = blockIdx.x * blockDim.x + threadIdx.x;
    if (e >= E) return;
    int t = eifbg[e], s = eifbg[E + e];   // tgt = row0, src = row1
    const float* x8 = eafb + (size_t)e * 8;
    float xv[8];
#pragma unroll
    for (int k = 0; k < 8; ++k) xv[k] = x8[k];
    float4 lt = *(const float4*)(at + (size_t)t * 4);
    float4 ls = *(const float4*)(asr + (size_t)s * 4);
    float o[4];
#pragma unroll
    for (int h = 0; h < 4; ++h) {
        float acc = cst[40 + h];
#pragma unroll
        for (int k = 0; k < 8; ++k) acc += xv[k] * cst[8 + h * 8 + k];
        o[h] = acc;
    }
    float4 ov;
    ov.x = lrelu(o[0] + lt.x + ls.x); ov.y = lrelu(o[1] + lt.y + ls.y);
    ov.z = lrelu(o[2] + lt.z + ls.z); ov.w = lrelu(o[3] + lt.w + ls.w);
    *(float4*)(lg + (size_t)e * 4) = ov;
}

// atom/frag-graph logits for real edges: eterm[h] = <EA[e,0:256], w[h, 64:320]>
// one wave per edge; full-wave reduction of 4 head dots.
__global__ void logits_edge_dot(const int* __restrict__ srcArr, const int* __restrict__ tgtArr,
        const float* __restrict__ EA, const float* __restrict__ w, int wstride,
        const float* __restrict__ at, const float* __restrict__ asr,
        float* __restrict__ lg, int E)
{
    int gw = (blockIdx.x * blockDim.x + threadIdx.x) >> 6;
    int lane = threadIdx.x & 63;
    if (gw >= E) return;
    float4 v = *(const float4*)(EA + (size_t)gw * 256 + lane * 4);
    const float* w0 = w + 0 * wstride + 64 + lane * 4;
    const float* w1 = w + 1 * wstride + 64 + lane * 4;
    const float* w2 = w + 2 * wstride + 64 + lane * 4;
    const float* w3 = w + 3 * wstride + 64 + lane * 4;
    float p0 = v.x * w0[0] + v.y * w0[1] + v.z * w0[2] + v.w * w0[3];
    float p1 = v.x * w1[0] + v.y * w1[1] + v.z * w1[2] + v.w * w1[3];
    float p2 = v.x * w2[0] + v.y * w2[1] + v.z * w2[2] + v.w * w2[3];
    float p3 = v.x * w3[0] + v.y * w3[1] + v.z * w3[2] + v.w * w3[3];
#pragma unroll
    for (int o = 1; o < 64; o <<= 1) {
        p0 += __shfl_xor(p0, o); p1 += __shfl_xor(p1, o);
        p2 += __shfl_xor(p2, o); p3 += __shfl_xor(p3, o);
    }
    if (lane == 0) {
        int t = tgtArr[gw], s = srcArr[gw];
        float4 lt = *(const float4*)(at + (size_t)t * 4);
        float4 ls = *(const float4*)(asr + (size_t)s * 4);
        float4 ov;
        ov.x = lrelu(p0 + lt.x + ls.x); ov.y = lrelu(p1 + lt.y + ls.y);
        ov.z = lrelu(p2 + lt.z + ls.z); ov.w = lrelu(p3 + lt.w + ls.w);
        *(float4*)(lg + (size_t)gw * 4) = ov;
    }
}

// self-loop logits (atom graph): eterm = 0
__global__ void logits_self(const float* __restrict__ at, const float* __restrict__ asr,
        float* __restrict__ lg, int base, int N)
{
    int n = blockIdx.x * blockDim.x + threadIdx.x;
    if (n >= N) return;
    float4 lt = *(const float4*)(at + (size_t)n * 4);
    float4 ls = *(const float4*)(asr + (size_t)n * 4);
    float4 o;
    o.x = lrelu(lt.x + ls.x); o.y = lrelu(lt.y + ls.y);
    o.z = lrelu(lt.z + ls.z); o.w = lrelu(lt.w + ls.w);
    *(float4*)(lg + (size_t)(base + n) * 4) = o;
}

// per-target linked lists (sort-free CSR substitute)
__global__ void build_list(const int* __restrict__ tgt, int E, int* __restrict__ head, int* __restrict__ nxt)
{
    int e = blockIdx.x * blockDim.x + threadIdx.x;
    if (e >= E) return;
    nxt[e] = atomicExch(&head[tgt[e]], e);
}
__global__ void build_list_self(int base, int N, int* __restrict__ head, int* __restrict__ nxt)
{
    int n = blockIdx.x * blockDim.x + threadIdx.x;
    if (n >= N) return;
    nxt[base + n] = atomicExch(&head[n], base + n);
}

// fused segment softmax + weighted gather-aggregate; one wave per target node.
// src of edge e: srcArr[e] for e<realE, else (e-realE) (atom-graph self loops).
__global__ void gat_aggregate(const int* __restrict__ head, const int* __restrict__ nxt,
        const float* __restrict__ lg, const int* __restrict__ srcArr, int realE,
        const unsigned short* __restrict__ Hn, float* __restrict__ out, int N)
{
    int gw = (blockIdx.x * blockDim.x + threadIdx.x) >> 6;
    int lane = threadIdx.x & 63;
    if (gw >= N) return;
    int hl = lane >> 4;
    float m = -3.0e38f;
    for (int e = head[gw]; e >= 0; e = nxt[e]) m = fmaxf(m, lg[(size_t)e * 4 + hl]);
    float s = 0.f;
    for (int e = head[gw]; e >= 0; e = nxt[e]) s += __expf(lg[(size_t)e * 4 + hl] - m);
    float a0 = 0.f, a1 = 0.f, a2 = 0.f, a3 = 0.f;
    for (int e = head[gw]; e >= 0; e = nxt[e]) {
        float wgt = __expf(lg[(size_t)e * 4 + hl] - m);
        int sn = (e < realE) ? srcArr[e] : (e - realE);
        ushort4 hv = *(const ushort4*)(Hn + (size_t)sn * 256 + lane * 4);
        a0 += wgt * bf2f(hv.x); a1 += wgt * bf2f(hv.y);
        a2 += wgt * bf2f(hv.z); a3 += wgt * bf2f(hv.w);
    }
    float inv = (s > 0.f) ? 1.f / s : 0.f;
    float4 o; o.x = a0 * inv; o.y = a1 * inv; o.z = a2 * inv; o.w = a3 * inv;
    *(float4*)(out + (size_t)gw * 256 + lane * 4) = o;
}

// x_frags_agg: plain segment sum of x_atoms_new rows (bf16 out, feeds frag GAT)
__global__ void seg_sum_frag(const int* __restrict__ head, const int* __restrict__ nxt,
        const float* __restrict__ X, unsigned short* __restrict__ Hf, int N)
{
    int gw = (blockIdx.x * blockDim.x + threadIdx.x) >> 6;
    int lane = threadIdx.x & 63;
    if (gw >= N) return;
    float a0 = 0.f, a1 = 0.f, a2 = 0.f, a3 = 0.f;
    for (int e = head[gw]; e >= 0; e = nxt[e]) {
        float4 v = *(const float4*)(X + (size_t)e * 256 + lane * 4);
        a0 += v.x; a1 += v.y; a2 += v.z; a3 += v.w;
    }
    ushort4 b; b.x = f2bf(a0); b.y = f2bf(a1); b.z = f2bf(a2); b.w = f2bf(a3);
    *(ushort4*)(Hf + (size_t)gw * 256 + lane * 4) = b;
}

extern "C" void kernel_launch(void* const* d_in, const int* in_sizes, int n_in,
                              void* d_out, int out_size, void* d_ws, size_t ws_size,
                              hipStream_t stream)
{
    const float* x_atoms = (const float*)d_in[0];
    const int*   ei      = (const int*)d_in[1];     // (2,EB) row0=src row1=tgt
    const int*   fi      = (const int*)d_in[3];     // (2,EF) row0=src row1=tgt
    const int*   a2f     = (const int*)d_in[5];
    const float* nfb     = (const float*)d_in[6];
    const int*   eibg    = (const int*)d_in[7];     // (2,EBG) row0=tgt row1=src
    const float* eabg    = (const float*)d_in[8];
    const float* nffb    = (const float*)d_in[9];
    const int*   eifbg   = (const int*)d_in[10];    // (2,EFBG) row0=tgt row1=src
    const float* eafbg   = (const float*)d_in[11];
    const float* W_pb    = (const float*)d_in[12];
    const float* b_pb    = (const float*)d_in[13];
    const float* W_eab   = (const float*)d_in[14];
    const float* b_eab   = (const float*)d_in[15];
    const float* a_b     = (const float*)d_in[16];
    const float* W_pa    = (const float*)d_in[17];
    const float* b_pa    = (const float*)d_in[18];
    const float* a_w     = (const float*)d_in[19];
    const float* W_pfb   = (const float*)d_in[20];
    const float* b_pfb   = (const float*)d_in[21];
    const float* W_eafb  = (const float*)d_in[22];
    const float* b_eafb  = (const float*)d_in[23];
    const float* f_a_b   = (const float*)d_in[24];
    const float* f_w     = (const float*)d_in[25];

    float* out        = (float*)d_out;
    float* out_atoms  = out;
    float* out_frags  = out + (size_t)NA * 256;
    float* out_bonds  = out + (size_t)(NA + NF) * 256;
    float* out_fbonds = out + (size_t)(NA + NF + EB) * 256;

    size_t off = 0;
    char* base = (char*)d_ws;
    auto alloc = [&](size_t bytes) -> char* {
        char* p = base + off; off += (bytes + 255) & ~(size_t)255; return p;
    };
    unsigned short* h_b  = (unsigned short*)alloc((size_t)EB * 256 * 2);
    unsigned short* h_a  = (unsigned short*)alloc((size_t)NA * 256 * 2);
    unsigned short* h_fb = (unsigned short*)alloc((size_t)EF * 256 * 2);
    unsigned short* h_f  = (unsigned short*)alloc((size_t)NF * 256 * 2);
    float* at_b = (float*)alloc((size_t)EB * 16);  float* as_b = (float*)alloc((size_t)EB * 16);
    float* at_a = (float*)alloc((size_t)NA * 16);  float* as_a = (float*)alloc((size_t)NA * 16);
    float* at_fb = (float*)alloc((size_t)EF * 16); float* as_fb = (float*)alloc((size_t)EF * 16);
    float* at_f = (float*)alloc((size_t)NF * 16);  float* as_f = (float*)alloc((size_t)NF * 16);
    float* lg_b  = (float*)alloc((size_t)EBG * 16);
    float* lg_a  = (float*)alloc((size_t)(EB + NA) * 16);
    float* lg_fb = (float*)alloc((size_t)EFBG * 16);
    float* lg_f  = (float*)alloc((size_t)EF * 16);
    int* heads = (int*)alloc((size_t)(EB + NA + EF + NF + NF) * 4);
    int* head_b = heads; int* head_a = heads + EB; int* head_fb = head_a + NA;
    int* head_f = head_fb + EF; int* head_fa = head_f + NF;
    int* nxt_b  = (int*)alloc((size_t)EBG * 4);
    int* nxt_a  = (int*)alloc((size_t)(EB + NA) * 4);
    int* nxt_fb = (int*)alloc((size_t)EFBG * 4);
    int* nxt_f  = (int*)alloc((size_t)EF * 4);
    int* nxt_fa = (int*)alloc((size_t)NA * 4);
    float* cst  = (float*)alloc(64 * 4);
    unsigned short* wf_pb  = (unsigned short*)alloc((size_t)65536 * 2);
    unsigned short* wf_pa  = (unsigned short*)alloc((size_t)65536 * 2);
    unsigned short* wf_pfb = (unsigned short*)alloc((size_t)65536 * 2);

    hipMemsetAsync(heads, 0xFF, (size_t)(EB + NA + EF + NF + NF) * 4, stream);

    compute_consts<<<1, 64, 0, stream>>>(a_b, W_eab, b_eab, f_a_b, W_eafb, b_eafb, cst);

    // one-time W -> bf16 fragment-order conversion (L2-resident, ~2us total)
    prep_w<<<32, 256, 0, stream>>>(W_pb,  wf_pb);
    prep_w<<<32, 256, 0, stream>>>(W_pa,  wf_pa);
    prep_w<<<32, 256, 0, stream>>>(W_pfb, wf_pfb);

    // dense projections (bf16 MFMA, register-resident B, HBM-BW-bound)
    gemm_bf16_v2<<<512, 512, 0, stream>>>(nfb,     wf_pb,  b_pb,  h_b,  EB);
    gemm_bf16_v2<<<512, 512, 0, stream>>>(x_atoms, wf_pa,  b_pa,  h_a,  NA);
    gemm_bf16_v2<<<512, 512, 0, stream>>>(nffb,    wf_pfb, b_pfb, h_fb, EF);

    // adjacency linked lists
    build_list<<<(EBG + 255) / 256, 256, 0, stream>>>(eibg, EBG, head_b, nxt_b);
    build_list<<<(EB + 255) / 256, 256, 0, stream>>>(ei + EB, EB, head_a, nxt_a);
    build_list_self<<<(NA + 255) / 256, 256, 0, stream>>>(EB, NA, head_a, nxt_a);
    build_list<<<(EFBG + 255) / 256, 256, 0, stream>>>(eifbg, EFBG, head_fb, nxt_fb);
    build_list<<<(EF + 255) / 256, 256, 0, stream>>>(fi + EF, EF, head_f, nxt_f);
    build_list<<<(NA + 255) / 256, 256, 0, stream>>>(a2f, NA, head_fa, nxt_fa);

    // ---- bond graph GAT -> new_bond_features ----
    node_alpha<<<(EB + 3) / 4, 256, 0, stream>>>(h_b, a_b, 192, 128, at_b, as_b, EB);
    logits_bond<<<(EBG + 255) / 256, 256, 0, stream>>>(eibg, eabg, at_b, as_b, cst, lg_b, EBG);
    gat_aggregate<<<(EB + 3) / 4, 256, 0, stream>>>(head_b, nxt_b, lg_b, eibg + EBG, EBG, h_b, out_bonds, EB);

    // ---- atom graph GAT -> x_atoms_new ----
    node_alpha<<<(NA + 3) / 4, 256, 0, stream>>>(h_a, a_w, 384, 320, at_a, as_a, NA);
    logits_edge_dot<<<(EB + 3) / 4, 256, 0, stream>>>(ei, ei + EB, out_bonds, a_w, 384, at_a, as_a, lg_a, EB);
    logits_self<<<(NA + 255) / 256, 256, 0, stream>>>(at_a, as_a, lg_a, EB, NA);
    gat_aggregate<<<(NA + 3) / 4, 256, 0, stream>>>(head_a, nxt_a, lg_a, ei, EB, h_a, out_atoms, NA);

    // ---- fragment pooling ----
    seg_sum_frag<<<(NF + 3) / 4, 256, 0, stream>>>(head_fa, nxt_fa, out_atoms, h_f, NF);

    // ---- fbond graph GAT -> new_fbond_features ----
    node_alpha<<<(EF + 3) / 4, 256, 0, stream>>>(h_fb, f_a_b, 192, 128, at_fb, as_fb, EF);
    logits_fbond<<<(EFBG + 255) / 256, 256, 0, stream>>>(eifbg, eafbg, at_fb, as_fb, cst, lg_fb, EFBG);
    gat_aggregate<<<(EF + 3) / 4, 256, 0, stream>>>(head_fb, nxt_fb, lg_fb, eifbg + EFBG, EFBG, h_fb, out_fbonds, EF);

    // ---- frag graph GAT -> x_frags_new ----
    node_alpha<<<(NF + 3) / 4, 256, 0, stream>>>(h_f, f_w, 384, 320, at_f, as_f, NF);
    logits_edge_dot<<<(EF + 3) / 4, 256, 0, stream>>>(fi, fi + EF, out_fbonds, f_w, 384, at_f, as_f, lg_f, EF);
    gat_aggregate<<<(NF + 3) / 4, 256, 0, stream>>>(head_f, nxt_f, lg_f, fi, EF, h_f, out_frags, NF);
}

// Round 2
// 1206.008 us; speedup vs baseline: 1.3964x; 1.0718x over previous
//
#include <hip/hip_runtime.h>

// Problem sizes (fixed by the reference)
#define NA   100000
#define EB   200000
#define EBG  400000
#define NF   20000
#define EF   60000
#define EFBG 120000

typedef __attribute__((ext_vector_type(8))) short short8;   // 8 x bf16 (4 VGPRs)
typedef __attribute__((ext_vector_type(4))) float f32x4;

__device__ __forceinline__ float bf2f(unsigned short u) {
    union { unsigned int i; float f; } c; c.i = ((unsigned int)u) << 16; return c.f;
}
__device__ __forceinline__ unsigned short f2bf(float f) {
    union { float f; unsigned int i; } c; c.f = f;
    unsigned int x = c.i + 0x7FFFu + ((c.i >> 16) & 1u);   // RNE
    return (unsigned short)(x >> 16);
}
__device__ __forceinline__ float lrelu(float v) { return v > 0.f ? v : 0.2f * v; }

// ---------------------------------------------------------------------------
// prep_w: convert W (256x256 f32, row-major [n][k]) to bf16 pre-swizzled into
// MFMA B-fragment order. Fragment id = wv*16 + ks*2 + nt  (wv=wave 0..7 owning
// cols wv*32.., ks=K-subtile 0..7, nt=n-tile 0..1). Element for lane (q,c):
//   B[n = wv*32 + nt*16 + c][k = ks*32 + q*8 + j], j=0..7  (C = A @ W^T)
// Layout: wf[(fid*64 + lane)*8 + j]  -> gemm loads one short8 per frag, coalesced.
// ---------------------------------------------------------------------------
__global__ void prep_w(const float* __restrict__ W, unsigned short* __restrict__ wf)
{
    int idx = blockIdx.x * blockDim.x + threadIdx.x;   // 8192 threads
    int lane = idx & 63;
    int fid  = idx >> 6;                               // 0..127
    int nt = fid & 1, ks = (fid >> 1) & 7, wv = fid >> 4;
    int n = wv * 32 + nt * 16 + (lane & 15);
    int k = ks * 32 + (lane >> 4) * 8;
    const float* src = W + (size_t)n * 256 + k;
    unsigned short* dst = wf + (size_t)idx * 8;
    ushort4 lo, hi;
    lo.x = f2bf(src[0]); lo.y = f2bf(src[1]); lo.z = f2bf(src[2]); lo.w = f2bf(src[3]);
    hi.x = f2bf(src[4]); hi.y = f2bf(src[5]); hi.z = f2bf(src[6]); hi.w = f2bf(src[7]);
    *(ushort4*)dst = lo; *(ushort4*)(dst + 4) = hi;
}

// ---------------------------------------------------------------------------
// GEMM v2: H = bf16( A(Mx256) @ W(256,256)^T + bias )
// 512 threads = 8 waves; wave wv owns cols [wv*32, wv*32+32).
// B fragments register-resident (loaded once per block from prep_w buffer).
// Grid-stride over M-tiles of 32 rows (all M here are multiples of 32).
// ---------------------------------------------------------------------------
#define GBM  32
#define GLDB 264

__global__ __launch_bounds__(512, 2) void gemm_bf16_v2(const float* __restrict__ A,
        const unsigned short* __restrict__ WF, const float* __restrict__ bias,
        unsigned short* __restrict__ Hout, int M)
{
    __shared__ __align__(16) unsigned short sA[GBM * GLDB];
    const int tid = threadIdx.x;
    const int wv = tid >> 6, lane = tid & 63;
    const int q = lane >> 4, c = lane & 15;

    // B fragments: 16 per wave = 64 VGPRs, loaded once (L2-resident 128KB)
    short8 bfr[8][2];
#pragma unroll
    for (int ks = 0; ks < 8; ++ks)
#pragma unroll
        for (int nt = 0; nt < 2; ++nt)
            bfr[ks][nt] = *(const short8*)(WF + (((size_t)((wv * 16 + ks * 2 + nt) * 64 + lane)) << 3));

    const float b0 = bias[wv * 32 + c];
    const float b1 = bias[wv * 32 + 16 + c];

    const int ntiles = M >> 5;
    for (int t = blockIdx.x; t < ntiles; t += gridDim.x) {
        const float* At = A + (size_t)t * GBM * 256;
        // stage 32x256 f32 -> bf16 LDS; each thread 4 coalesced float4 loads
#pragma unroll
        for (int i = 0; i < 4; ++i) {
            int f4 = tid + i * 512;
            int row = f4 >> 6, col = (f4 & 63) << 2;     // col in floats
            f32x4 v = *(const f32x4*)(At + row * 256 + col);
            union { ushort4 u4; unsigned int u[2]; } pk;
            asm("v_cvt_pk_bf16_f32 %0, %1, %2" : "=v"(pk.u[0]) : "v"(v.x), "v"(v.y));
            asm("v_cvt_pk_bf16_f32 %0, %1, %2" : "=v"(pk.u[1]) : "v"(v.z), "v"(v.w));
            *(ushort4*)&sA[row * GLDB + col] = pk.u4;
        }
        __syncthreads();

        f32x4 acc00 = (f32x4){0.f,0.f,0.f,0.f}, acc01 = (f32x4){0.f,0.f,0.f,0.f};
        f32x4 acc10 = (f32x4){0.f,0.f,0.f,0.f}, acc11 = (f32x4){0.f,0.f,0.f,0.f};
#pragma unroll
        for (int ks = 0; ks < 8; ++ks) {
            short8 a0 = *(const short8*)&sA[(c)      * GLDB + ks * 32 + q * 8];
            short8 a1 = *(const short8*)&sA[(16 + c) * GLDB + ks * 32 + q * 8];
            acc00 = __builtin_amdgcn_mfma_f32_16x16x32_bf16(a0, bfr[ks][0], acc00, 0, 0, 0);
            acc01 = __builtin_amdgcn_mfma_f32_16x16x32_bf16(a0, bfr[ks][1], acc01, 0, 0, 0);
            acc10 = __builtin_amdgcn_mfma_f32_16x16x32_bf16(a1, bfr[ks][0], acc10, 0, 0, 0);
            acc11 = __builtin_amdgcn_mfma_f32_16x16x32_bf16(a1, bfr[ks][1], acc11, 0, 0, 0);
        }
        __syncthreads();

        // epilogue: C/D layout col=lane&15, row=quad*4+reg  [m89-verified]
        unsigned short* Ht = Hout + (size_t)t * GBM * 256;
        const int col0 = wv * 32 + c, col1 = wv * 32 + 16 + c;
#pragma unroll
        for (int r = 0; r < 4; ++r) {
            int row0 = (q * 4 + r) * 256;
            int row1 = (16 + q * 4 + r) * 256;
            Ht[row0 + col0] = f2bf(acc00[r] + b0);
            Ht[row0 + col1] = f2bf(acc01[r] + b1);
            Ht[row1 + col0] = f2bf(acc10[r] + b0);
            Ht[row1 + col1] = f2bf(acc11[r] + b1);
        }
    }
}

// ---------------------------------------------------------------------------
// Per-node alpha terms: at[n,h] = <h[n,h,:], w[h, 0:64]>, as[n,h] = <h[n,h,:], w[h, wsoff:wsoff+64]>
// One wave per node; lane l covers dims 4l..4l+3 (head = l/16); 16-lane reduce.
// ---------------------------------------------------------------------------
__global__ void node_alpha(const unsigned short* __restrict__ Hn, const float* __restrict__ w,
        int wstride, int wsoff, float* __restrict__ at, float* __restrict__ asr, int N)
{
    int gw = (blockIdx.x * blockDim.x + threadIdx.x) >> 6;
    int lane = threadIdx.x & 63;
    if (gw >= N) return;
    int hl = lane >> 4, l16 = lane & 15;
    ushort4 hu = *(const ushort4*)(Hn + (size_t)gw * 256 + lane * 4);
    float h0 = bf2f(hu.x), h1 = bf2f(hu.y), h2 = bf2f(hu.z), h3 = bf2f(hu.w);
    const float* wt = w + hl * wstride + l16 * 4;
    const float* wsv = wt + wsoff;
    float pt = h0 * wt[0] + h1 * wt[1] + h2 * wt[2] + h3 * wt[3];
    float ps = h0 * wsv[0] + h1 * wsv[1] + h2 * wsv[2] + h3 * wsv[3];
#pragma unroll
    for (int o = 1; o < 16; o <<= 1) { pt += __shfl_xor(pt, o); ps += __shfl_xor(ps, o); }
    if (l16 == 0) { at[(size_t)gw * 4 + hl] = pt; asr[(size_t)gw * 4 + hl] = ps; }
}

// tiny per-launch constant folding:
// cst[0..3]=c1b (x * this per head), cst[4..7]=c0b, cst[8..39]=d1fb[h*8+k], cst[40..43]=c0fb
__global__ void compute_consts(const float* __restrict__ a_b, const float* __restrict__ W_eab,
        const float* __restrict__ b_eab, const float* __restrict__ f_a_b,
        const float* __restrict__ W_eafb, const float* __restrict__ b_eafb, float* __restrict__ cst)
{
    int t = threadIdx.x;
    if (t < 4) {
        float s1 = 0.f, s0 = 0.f, sc = 0.f;
        for (int d = 0; d < 64; ++d) {
            float we = a_b[t * 192 + 64 + d];
            s1 += we * W_eab[d];
            s0 += we * b_eab[d];
            sc += f_a_b[t * 192 + 64 + d] * b_eafb[d];
        }
        cst[t] = s1; cst[4 + t] = s0; cst[40 + t] = sc;
    }
    if (t < 32) {
        int h = t >> 3, k = t & 7;
        float s = 0.f;
        for (int d = 0; d < 64; ++d) s += f_a_b[h * 192 + 64 + d] * W_eafb[d * 8 + k];
        cst[8 + t] = s;
    }
}

// bond-graph logits: edge attr is scalar -> eterm = x*c1[h] + c0[h]
__global__ void logits_bond(const int* __restrict__ eibg, const float* __restrict__ eab,
        const float* __restrict__ at, const float* __restrict__ asr,
        const float* __restrict__ cst, float* __restrict__ lg, int E)
{
    int e = blockIdx.x * blockDim.x + threadIdx.x;
    if (e >= E) return;
    int t = eibg[e], s = eibg[E + e];     // tgt = row0, src = row1
    float x = eab[e];
    float4 lt = *(const float4*)(at + (size_t)t * 4);
    float4 ls = *(const float4*)(asr + (size_t)s * 4);
    float4 o;
    o.x = lrelu(lt.x + ls.x + x * cst[0] + cst[4]);
    o.y = lrelu(lt.y + ls.y + x * cst[1] + cst[5]);
    o.z = lrelu(lt.z + ls.z + x * cst[2] + cst[6]);
    o.w = lrelu(lt.w + ls.w + x * cst[3] + cst[7]);
    *(float4*)(lg + (size_t)e * 4) = o;
}

// fbond-graph logits: 8-dim edge attr -> eterm = x8 . d1[h] + c0[h]
__global__ void logits_fbond(const int* __restrict__ eifbg, const float* __restrict__ eafb,
        const float* __restrict__ at, const float* __restrict__ asr,
        const float* __restrict__ cst, float* __restrict__ lg, int E)
{
    int e = blockIdx.x * blockDim.x + threadIdx.x;
    if (e >= E) return;
    int t = eifbg[e], s = eifbg[E + e];   // tgt = row0, src = row1
    const float* x8 = eafb + (size_t)e * 8;
    float xv[8];
#pragma unroll
    for (int k = 0; k < 8; ++k) xv[k] = x8[k];
    float4 lt = *(const float4*)(at + (size_t)t * 4);
    float4 ls = *(const float4*)(asr + (size_t)s * 4);
    float o[4];
#pragma unroll
    for (int h = 0; h < 4; ++h) {
        float acc = cst[40 + h];
#pragma unroll
        for (int k = 0; k < 8; ++k) acc += xv[k] * cst[8 + h * 8 + k];
        o[h] = acc;
    }
    float4 ov;
    ov.x = lrelu(o[0] + lt.x + ls.x); ov.y = lrelu(o[1] + lt.y + ls.y);
    ov.z = lrelu(o[2] + lt.z + ls.z); ov.w = lrelu(o[3] + lt.w + ls.w);
    *(float4*)(lg + (size_t)e * 4) = ov;
}

// atom/frag-graph logits for real edges: eterm[h] = <EA[e,0:256], w[h, 64:320]>
// one wave per edge; full-wave reduction of 4 head dots.
__global__ void logits_edge_dot(const int* __restrict__ srcArr, const int* __restrict__ tgtArr,
        const float* __restrict__ EA, const float* __restrict__ w, int wstride,
        const float* __restrict__ at, const float* __restrict__ asr,
        float* __restrict__ lg, int E)
{
    int gw = (blockIdx.x * blockDim.x + threadIdx.x) >> 6;
    int lane = threadIdx.x & 63;
    if (gw >= E) return;
    float4 v = *(const float4*)(EA + (size_t)gw * 256 + lane * 4);
    const float* w0 = w + 0 * wstride + 64 + lane * 4;
    const float* w1 = w + 1 * wstride + 64 + lane * 4;
    const float* w2 = w + 2 * wstride + 64 + lane * 4;
    const float* w3 = w + 3 * wstride + 64 + lane * 4;
    float p0 = v.x * w0[0] + v.y * w0[1] + v.z * w0[2] + v.w * w0[3];
    float p1 = v.x * w1[0] + v.y * w1[1] + v.z * w1[2] + v.w * w1[3];
    float p2 = v.x * w2[0] + v.y * w2[1] + v.z * w2[2] + v.w * w2[3];
    float p3 = v.x * w3[0] + v.y * w3[1] + v.z * w3[2] + v.w * w3[3];
#pragma unroll
    for (int o = 1; o < 64; o <<= 1) {
        p0 += __shfl_xor(p0, o); p1 += __shfl_xor(p1, o);
        p2 += __shfl_xor(p2, o); p3 += __shfl_xor(p3, o);
    }
    if (lane == 0) {
        int t = tgtArr[gw], s = srcArr[gw];
        float4 lt = *(const float4*)(at + (size_t)t * 4);
        float4 ls = *(const float4*)(asr + (size_t)s * 4);
        float4 ov;
        ov.x = lrelu(p0 + lt.x + ls.x); ov.y = lrelu(p1 + lt.y + ls.y);
        ov.z = lrelu(p2 + lt.z + ls.z); ov.w = lrelu(p3 + lt.w + ls.w);
        *(float4*)(lg + (size_t)gw * 4) = ov;
    }
}

// self-loop logits (atom graph): eterm = 0
__global__ void logits_self(const float* __restrict__ at, const float* __restrict__ asr,
        float* __restrict__ lg, int base, int N)
{
    int n = blockIdx.x * blockDim.x + threadIdx.x;
    if (n >= N) return;
    float4 lt = *(const float4*)(at + (size_t)n * 4);
    float4 ls = *(const float4*)(asr + (size_t)n * 4);
    float4 o;
    o.x = lrelu(lt.x + ls.x); o.y = lrelu(lt.y + ls.y);
    o.z = lrelu(lt.z + ls.z); o.w = lrelu(lt.w + ls.w);
    *(float4*)(lg + (size_t)(base + n) * 4) = o;
}

// per-target linked lists (sort-free CSR substitute)
__global__ void build_list(const int* __restrict__ tgt, int E, int* __restrict__ head, int* __restrict__ nxt)
{
    int e = blockIdx.x * blockDim.x + threadIdx.x;
    if (e >= E) return;
    nxt[e] = atomicExch(&head[tgt[e]], e);
}
__global__ void build_list_self(int base, int N, int* __restrict__ head, int* __restrict__ nxt)
{
    int n = blockIdx.x * blockDim.x + threadIdx.x;
    if (n >= N) return;
    nxt[base + n] = atomicExch(&head[n], base + n);
}

// fused segment softmax + weighted gather-aggregate; one wave per target node.
// SINGLE online-softmax traversal (flash-attention recurrence):
//   mn = max(m,x); r = exp(m-mn); w = exp(x-mn); s = s*r + w; a = a*r + w*h[src]
// Branchless; m init -3e38 makes first r==0, so recurrence is exact from start.
// src of edge e: srcArr[e] for e<realE, else (e-realE) (atom-graph self loops).
__global__ void gat_aggregate(const int* __restrict__ head, const int* __restrict__ nxt,
        const float* __restrict__ lg, const int* __restrict__ srcArr, int realE,
        const unsigned short* __restrict__ Hn, float* __restrict__ out, int N)
{
    int gw = (blockIdx.x * blockDim.x + threadIdx.x) >> 6;
    int lane = threadIdx.x & 63;
    if (gw >= N) return;
    int hl = lane >> 4;
    float m = -3.0e38f, s = 0.f;
    float a0 = 0.f, a1 = 0.f, a2 = 0.f, a3 = 0.f;
    int e = head[gw];
    while (e >= 0) {
        int en = nxt[e];                                   // issue chase load early
        float x = lg[(size_t)e * 4 + hl];
        int sn = (e < realE) ? srcArr[e] : (e - realE);
        ushort4 hv = *(const ushort4*)(Hn + (size_t)sn * 256 + lane * 4);
        float mn = fmaxf(m, x);
        float r  = __expf(m - mn);                         // 1 when m>=x, 0 on first edge
        float wg = __expf(x - mn);
        s  = s  * r + wg;
        a0 = a0 * r + wg * bf2f(hv.x);
        a1 = a1 * r + wg * bf2f(hv.y);
        a2 = a2 * r + wg * bf2f(hv.z);
        a3 = a3 * r + wg * bf2f(hv.w);
        m = mn;
        e = en;
    }
    float inv = (s > 0.f) ? 1.f / s : 0.f;
    float4 o; o.x = a0 * inv; o.y = a1 * inv; o.z = a2 * inv; o.w = a3 * inv;
    *(float4*)(out + (size_t)gw * 256 + lane * 4) = o;
}

// x_frags_agg: plain segment sum of x_atoms_new rows (bf16 out, feeds frag GAT)
__global__ void seg_sum_frag(const int* __restrict__ head, const int* __restrict__ nxt,
        const float* __restrict__ X, unsigned short* __restrict__ Hf, int N)
{
    int gw = (blockIdx.x * blockDim.x + threadIdx.x) >> 6;
    int lane = threadIdx.x & 63;
    if (gw >= N) return;
    float a0 = 0.f, a1 = 0.f, a2 = 0.f, a3 = 0.f;
    for (int e = head[gw]; e >= 0; e = nxt[e]) {
        float4 v = *(const float4*)(X + (size_t)e * 256 + lane * 4);
        a0 += v.x; a1 += v.y; a2 += v.z; a3 += v.w;
    }
    ushort4 b; b.x = f2bf(a0); b.y = f2bf(a1); b.z = f2bf(a2); b.w = f2bf(a3);
    *(ushort4*)(Hf + (size_t)gw * 256 + lane * 4) = b;
}

extern "C" void kernel_launch(void* const* d_in, const int* in_sizes, int n_in,
                              void* d_out, int out_size, void* d_ws, size_t ws_size,
                              hipStream_t stream)
{
    const float* x_atoms = (const float*)d_in[0];
    const int*   ei      = (const int*)d_in[1];     // (2,EB) row0=src row1=tgt
    const int*   fi      = (const int*)d_in[3];     // (2,EF) row0=src row1=tgt
    const int*   a2f     = (const int*)d_in[5];
    const float* nfb     = (const float*)d_in[6];
    const int*   eibg    = (const int*)d_in[7];     // (2,EBG) row0=tgt row1=src
    const float* eabg    = (const float*)d_in[8];
    const float* nffb    = (const float*)d_in[9];
    const int*   eifbg   = (const int*)d_in[10];    // (2,EFBG) row0=tgt row1=src
    const float* eafbg   = (const float*)d_in[11];
    const float* W_pb    = (const float*)d_in[12];
    const float* b_pb    = (const float*)d_in[13];
    const float* W_eab   = (const float*)d_in[14];
    const float* b_eab   = (const float*)d_in[15];
    const float* a_b     = (const float*)d_in[16];
    const float* W_pa    = (const float*)d_in[17];
    const float* b_pa    = (const float*)d_in[18];
    const float* a_w     = (const float*)d_in[19];
    const float* W_pfb   = (const float*)d_in[20];
    const float* b_pfb   = (const float*)d_in[21];
    const float* W_eafb  = (const float*)d_in[22];
    const float* b_eafb  = (const float*)d_in[23];
    const float* f_a_b   = (const float*)d_in[24];
    const float* f_w     = (const float*)d_in[25];

    float* out        = (float*)d_out;
    float* out_atoms  = out;
    float* out_frags  = out + (size_t)NA * 256;
    float* out_bonds  = out + (size_t)(NA + NF) * 256;
    float* out_fbonds = out + (size_t)(NA + NF + EB) * 256;

    size_t off = 0;
    char* base = (char*)d_ws;
    auto alloc = [&](size_t bytes) -> char* {
        char* p = base + off; off += (bytes + 255) & ~(size_t)255; return p;
    };
    unsigned short* h_b  = (unsigned short*)alloc((size_t)EB * 256 * 2);
    unsigned short* h_a  = (unsigned short*)alloc((size_t)NA * 256 * 2);
    unsigned short* h_fb = (unsigned short*)alloc((size_t)EF * 256 * 2);
    unsigned short* h_f  = (unsigned short*)alloc((size_t)NF * 256 * 2);
    float* at_b = (float*)alloc((size_t)EB * 16);  float* as_b = (float*)alloc((size_t)EB * 16);
    float* at_a = (float*)alloc((size_t)NA * 16);  float* as_a = (float*)alloc((size_t)NA * 16);
    float* at_fb = (float*)alloc((size_t)EF * 16); float* as_fb = (float*)alloc((size_t)EF * 16);
    float* at_f = (float*)alloc((size_t)NF * 16);  float* as_f = (float*)alloc((size_t)NF * 16);
    float* lg_b  = (float*)alloc((size_t)EBG * 16);
    float* lg_a  = (float*)alloc((size_t)(EB + NA) * 16);
    float* lg_fb = (float*)alloc((size_t)EFBG * 16);
    float* lg_f  = (float*)alloc((size_t)EF * 16);
    int* heads = (int*)alloc((size_t)(EB + NA + EF + NF + NF) * 4);
    int* head_b = heads; int* head_a = heads + EB; int* head_fb = head_a + NA;
    int* head_f = head_fb + EF; int* head_fa = head_f + NF;
    int* nxt_b  = (int*)alloc((size_t)EBG * 4);
    int* nxt_a  = (int*)alloc((size_t)(EB + NA) * 4);
    int* nxt_fb = (int*)alloc((size_t)EFBG * 4);
    int* nxt_f  = (int*)alloc((size_t)EF * 4);
    int* nxt_fa = (int*)alloc((size_t)NA * 4);
    float* cst  = (float*)alloc(64 * 4);
    unsigned short* wf_pb  = (unsigned short*)alloc((size_t)65536 * 2);
    unsigned short* wf_pa  = (unsigned short*)alloc((size_t)65536 * 2);
    unsigned short* wf_pfb = (unsigned short*)alloc((size_t)65536 * 2);

    hipMemsetAsync(heads, 0xFF, (size_t)(EB + NA + EF + NF + NF) * 4, stream);

    compute_consts<<<1, 64, 0, stream>>>(a_b, W_eab, b_eab, f_a_b, W_eafb, b_eafb, cst);

    // one-time W -> bf16 fragment-order conversion (L2-resident, ~2us total)
    prep_w<<<32, 256, 0, stream>>>(W_pb,  wf_pb);
    prep_w<<<32, 256, 0, stream>>>(W_pa,  wf_pa);
    prep_w<<<32, 256, 0, stream>>>(W_pfb, wf_pfb);

    // dense projections (bf16 MFMA, register-resident B, HBM-BW-bound)
    gemm_bf16_v2<<<512, 512, 0, stream>>>(nfb,     wf_pb,  b_pb,  h_b,  EB);
    gemm_bf16_v2<<<512, 512, 0, stream>>>(x_atoms, wf_pa,  b_pa,  h_a,  NA);
    gemm_bf16_v2<<<512, 512, 0, stream>>>(nffb,    wf_pfb, b_pfb, h_fb, EF);

    // adjacency linked lists
    build_list<<<(EBG + 255) / 256, 256, 0, stream>>>(eibg, EBG, head_b, nxt_b);
    build_list<<<(EB + 255) / 256, 256, 0, stream>>>(ei + EB, EB, head_a, nxt_a);
    build_list_self<<<(NA + 255) / 256, 256, 0, stream>>>(EB, NA, head_a, nxt_a);
    build_list<<<(EFBG + 255) / 256, 256, 0, stream>>>(eifbg, EFBG, head_fb, nxt_fb);
    build_list<<<(EF + 255) / 256, 256, 0, stream>>>(fi + EF, EF, head_f, nxt_f);
    build_list<<<(NA + 255) / 256, 256, 0, stream>>>(a2f, NA, head_fa, nxt_fa);

    // ---- bond graph GAT -> new_bond_features ----
    node_alpha<<<(EB + 3) / 4, 256, 0, stream>>>(h_b, a_b, 192, 128, at_b, as_b, EB);
    logits_bond<<<(EBG + 255) / 256, 256, 0, stream>>>(eibg, eabg, at_b, as_b, cst, lg_b, EBG);
    gat_aggregate<<<(EB + 3) / 4, 256, 0, stream>>>(head_b, nxt_b, lg_b, eibg + EBG, EBG, h_b, out_bonds, EB);

    // ---- atom graph GAT -> x_atoms_new ----
    node_alpha<<<(NA + 3) / 4, 256, 0, stream>>>(h_a, a_w, 384, 320, at_a, as_a, NA);
    logits_edge_dot<<<(EB + 3) / 4, 256, 0, stream>>>(ei, ei + EB, out_bonds, a_w, 384, at_a, as_a, lg_a, EB);
    logits_self<<<(NA + 255) / 256, 256, 0, stream>>>(at_a, as_a, lg_a, EB, NA);
    gat_aggregate<<<(NA + 3) / 4, 256, 0, stream>>>(head_a, nxt_a, lg_a, ei, EB, h_a, out_atoms, NA);

    // ---- fragment pooling ----
    seg_sum_frag<<<(NF + 3) / 4, 256, 0, stream>>>(head_fa, nxt_fa, out_atoms, h_f, NF);

    // ---- fbond graph GAT -> new_fbond_features ----
    node_alpha<<<(EF + 3) / 4, 256, 0, stream>>>(h_fb, f_a_b, 192, 128, at_fb, as_fb, EF);
    logits_fbond<<<(EFBG + 255) / 256, 256, 0, stream>>>(eifbg, eafbg, at_fb, as_fb, cst, lg_fb, EFBG);
    gat_aggregate<<<(EF + 3) / 4, 256, 0, stream>>>(head_fb, nxt_fb, lg_fb, eifbg + EFBG, EFBG, h_fb, out_fbonds, EF);

    // ---- frag graph GAT -> x_frags_new ----
    node_alpha<<<(NF + 3) / 4, 256, 0, stream>>>(h_f, f_w, 384, 320, at_f, as_f, NF);
    logits_edge_dot<<<(EF + 3) / 4, 256, 0, stream>>>(fi, fi + EF, out_fbonds, f_w, 384, at_f, as_f, lg_f, EF);
    gat_aggregate<<<(NF + 3) / 4, 256, 0, stream>>>(head_f, nxt_f, lg_f, fi, EF, h_f, out_frags, NF);
}